// Round 6
// baseline (108.356 us; speedup 1.0000x reference)
//
#include <hip/hip_runtime.h>
#include <hip/hip_bf16.h>

// ---------------------------------------------------------------------------
// Metric_Loss: two fused (X X^T/128 -> exp(1+.) -> row-sum) passes + pair combine.
// B=8192, E=128, P=4096.  Output: scalar f32 = metric_tt + metric_st.
//
// Round 6: LDS-free GEMM + register double-buffering. Tile t+1's B-fragments
// are loaded into the alternate register buffer BEFORE tile t's MFMA+epilogue
// (~400 cyc of issue work), hiding L1/L2 latency that made R5 80% stall
// (MfmaUtil 8.9, VALUBusy 12.7, VGPR=44 -> no prefetch regs allocated).
// Static pA/pB naming (unrolled 2x loop) keeps buffers in registers.
// 1024 blocks = exactly 4/CU resident, zero tail.
//
// ws layout:
//   [0, 2MB)        Xt bf16   [8192][128]   scaled by sqrt(log2e/128)
//   [2MB, 4MB)      Xm bf16   [8192][128]   (mixed: even=text, odd=shape[r>>1])
//   [4MB, 4MB+64KB) R f32     [2][8192]     row sums of exp(1+D)
// ---------------------------------------------------------------------------

#define B_ROWS 8192
#define E_COLS 128
#define P_PAIRS 4096
#define NSTRIP 128              // 64-row strips

using short8 = __attribute__((ext_vector_type(8))) short;
using f32x4  = __attribute__((ext_vector_type(4))) float;

// sqrt(log2(e)/128): MFMA yields acc = D*log2(e); exp(1+D) = e * exp2(acc)
#define BF_SCALE 0.106164482742544f
#define EULER    2.718281828459045f

__device__ __forceinline__ unsigned short f2bf(float f) {
    unsigned u = __builtin_bit_cast(unsigned, f);
    unsigned r = (u + 0x7fffu + ((u >> 16) & 1u)) >> 16;   // RNE
    return (unsigned short)r;
}

// --------------------------- conversion kernel -----------------------------
__global__ void convert_kernel(const float* __restrict__ text,
                               const float* __restrict__ shape,
                               unsigned short* __restrict__ Xt,
                               unsigned short* __restrict__ Xm,
                               float* __restrict__ R,
                               float* __restrict__ out) {
    int idx = blockIdx.x * blockDim.x + threadIdx.x;     // one float4 per thread
    if (idx < 4096) {                                    // zero R (2*8192 f32)
        float4 z; z.x = z.y = z.z = z.w = 0.f;
        ((float4*)R)[idx] = z;
    }
    if (idx == 0) *out = 0.f;
    int e = idx * 4;
    if (e >= B_ROWS * E_COLS) return;
    float4 t = *(const float4*)(text + e);
    ushort4 tb;
    tb.x = f2bf(t.x * BF_SCALE); tb.y = f2bf(t.y * BF_SCALE);
    tb.z = f2bf(t.z * BF_SCALE); tb.w = f2bf(t.w * BF_SCALE);
    *(ushort4*)(Xt + e) = tb;
    int row = e >> 7;
    if (row & 1) {
        int col = e & 127;
        float4 s = *(const float4*)(shape + (row >> 1) * E_COLS + col);
        ushort4 sb;
        sb.x = f2bf(s.x * BF_SCALE); sb.y = f2bf(s.y * BF_SCALE);
        sb.z = f2bf(s.z * BF_SCALE); sb.w = f2bf(s.w * BF_SCALE);
        *(ushort4*)(Xm + e) = sb;
    } else {
        *(ushort4*)(Xm + e) = tb;
    }
}

// --------------------------- fused GEMM + rowsum (LDS-free, reg-dbuf) ------
// Block = (strip bm in 0..127, split h in 0..3, layer l). Strip = 64 A-rows.
// Tiles (bm, bn=(bm+t)&127): t in {1..63} each unordered pair once; t==64
// gated bm<64; t==0 diagonal (h==0 only). Per wave: 32x32 output quadrant.
__launch_bounds__(256, 4)
__global__ void gemm_rowsum_kernel(const unsigned short* __restrict__ Xt,
                                   const unsigned short* __restrict__ Xm,
                                   float* __restrict__ R) {
    const int bm = blockIdx.x, h = blockIdx.y, l = blockIdx.z;
    const unsigned short* X = l ? Xm : Xt;

    const int tid  = threadIdx.x;
    const int lane = tid & 63;
    const int w    = tid >> 6;
    const int wr   = w >> 1, wc = w & 1;
    const int rA   = wr * 32 + (lane & 15);      // A-row within strip
    const int rB   = wc * 32 + (lane & 15);      // B-row (= output col) within strip
    const int ke   = (lane >> 4) * 8;            // element offset of lane's k-slice

    const int t0 = (h == 0) ? 4 : h;
    const int N  = (h == 0) ? (bm < 64 ? 16 : 15) : 16;   // off-diag tile count

    // ---- hoist A fragments straight from global ----
    const unsigned short* Ab = X + (size_t)bm * (64 * E_COLS);
    short8 afr[4][2];
#pragma unroll
    for (int kk = 0; kk < 4; ++kk)
#pragma unroll
        for (int m = 0; m < 2; ++m)
            afr[kk][m] = *(const short8*)(Ab + (rA + m * 16) * E_COLS + kk * 32 + ke);

    float s_r[2][4] = {{0.f}};                   // persistent row partials [m][j]

    auto tileofs = [&](int idx) -> int { return (bm + t0 + 4 * idx) & 127; };

    auto loadB = [&](short8 (&dst)[4][2], int bn) {
        const unsigned short* Bb = X + (size_t)bn * (64 * E_COLS);
#pragma unroll
        for (int kk = 0; kk < 4; ++kk)
#pragma unroll
            for (int n = 0; n < 2; ++n)
                dst[kk][n] = *(const short8*)(Bb + (rB + n * 16) * E_COLS + kk * 32 + ke);
    };

    auto compute_epi = [&](const short8 (&bfr)[4][2], int bn) {
        f32x4 acc[2][2] = {};
#pragma unroll
        for (int kk = 0; kk < 4; ++kk)
#pragma unroll
            for (int m = 0; m < 2; ++m)
#pragma unroll
                for (int n = 0; n < 2; ++n)
                    acc[m][n] = __builtin_amdgcn_mfma_f32_16x16x32_bf16(
                        afr[kk][m], bfr[kk][n], acc[m][n], 0, 0, 0);
        float s_c[2] = {0.f, 0.f};
#pragma unroll
        for (int m = 0; m < 2; ++m)
#pragma unroll
            for (int n = 0; n < 2; ++n)
#pragma unroll
                for (int j = 0; j < 4; ++j) {
                    float e2 = __builtin_amdgcn_exp2f(acc[m][n][j]);
                    s_r[m][j] += e2;
                    s_c[n] += e2;
                }
#pragma unroll
        for (int n = 0; n < 2; ++n) {
            float v = s_c[n];
            v += __shfl_xor(v, 16, 64);
            v += __shfl_xor(v, 32, 64);
            if (lane < 16) {
                int gcol = bn * 64 + wc * 32 + n * 16 + lane;
                atomicAdd(&R[l * B_ROWS + gcol], EULER * v);
            }
        }
    };

    // ---- diagonal tile (h==0): B-frags from A strip; rows only ----
    if (h == 0) {
        short8 bfr[4][2];
        loadB(bfr, bm);
        f32x4 acc[2][2] = {};
#pragma unroll
        for (int kk = 0; kk < 4; ++kk)
#pragma unroll
            for (int m = 0; m < 2; ++m)
#pragma unroll
                for (int n = 0; n < 2; ++n)
                    acc[m][n] = __builtin_amdgcn_mfma_f32_16x16x32_bf16(
                        afr[kk][m], bfr[kk][n], acc[m][n], 0, 0, 0);
#pragma unroll
        for (int m = 0; m < 2; ++m)
#pragma unroll
            for (int n = 0; n < 2; ++n)
#pragma unroll
                for (int j = 0; j < 4; ++j)
                    s_r[m][j] += __builtin_amdgcn_exp2f(acc[m][n][j]);
    }

    // ---- off-diagonal tiles: register double-buffered stream ----
    short8 pA[4][2], pB[4][2];
    loadB(pA, tileofs(0));
    int idx = 0;
    while (idx < N) {
        // even iteration: consume pA, prefetch into pB
        if (idx + 1 < N) loadB(pB, tileofs(idx + 1));
        compute_epi(pA, tileofs(idx));
        ++idx;
        if (idx >= N) break;
        // odd iteration: consume pB, prefetch into pA
        if (idx + 1 < N) loadB(pA, tileofs(idx + 1));
        compute_epi(pB, tileofs(idx));
        ++idx;
    }

    // ---- final row reduction (once per block) ----
#pragma unroll
    for (int m = 0; m < 2; ++m)
#pragma unroll
        for (int j = 0; j < 4; ++j) {
            float v = s_r[m][j];
            v += __shfl_xor(v, 1, 64);
            v += __shfl_xor(v, 2, 64);
            v += __shfl_xor(v, 4, 64);
            v += __shfl_xor(v, 8, 64);
            if ((lane & 15) == 0) {
                int grow = bm * 64 + wr * 32 + m * 16 + (lane >> 4) * 4 + j;
                atomicAdd(&R[l * B_ROWS + grow], EULER * v);
            }
        }
}

// --------------------------- finalize --------------------------------------
__global__ void finalize_kernel(const float* __restrict__ text,
                                const float* __restrict__ shape,
                                const float* __restrict__ R,
                                float* __restrict__ out) {
    const int tid = threadIdx.x;
    const int lane = tid & 63;
    const int w = tid >> 6;
    const int waveGlobal = blockIdx.x * 4 + w;   // 1024 waves total
    const float inv128 = 0.0078125f;
    float accum = 0.f;

    for (int task = waveGlobal; task < 2 * P_PAIRS; task += 1024) {
        int l = task >> 12;
        int p = task & (P_PAIRS - 1);
        const float* a = text + (2 * p) * E_COLS;                       // even row: always text
        const float* b = l ? (shape + p * E_COLS) : (text + (2 * p + 1) * E_COLS);
        float2 av = *(const float2*)(a + lane * 2);
        float2 bv = *(const float2*)(b + lane * 2);
        float dii = av.x * av.x + av.y * av.y;
        float djj = bv.x * bv.x + bv.y * bv.y;
        float dij = av.x * bv.x + av.y * bv.y;
#pragma unroll
        for (int sh = 1; sh < 64; sh <<= 1) {
            dii += __shfl_xor(dii, sh, 64);
            djj += __shfl_xor(djj, sh, 64);
            dij += __shfl_xor(dij, sh, 64);
        }
        if (lane == 0) {
            float Dii = dii * inv128, Djj = djj * inv128, Dij = dij * inv128;
            float S = R[l * B_ROWS + 2 * p] + R[l * B_ROWS + 2 * p + 1]
                    - (__expf(1.f + Dii) + 2.f * __expf(1.f + Dij) + __expf(1.f + Djj));
            float J = __logf(S) - Dij;
            accum += 0.5f * J * J * (1.0f / (float)P_PAIRS);
        }
    }

    __shared__ float red[4];
    if (lane == 0) red[w] = accum;
    __syncthreads();
    if (tid == 0) {
        atomicAdd(out, red[0] + red[1] + red[2] + red[3]);
    }
}

// --------------------------- launch ----------------------------------------
extern "C" void kernel_launch(void* const* d_in, const int* in_sizes, int n_in,
                              void* d_out, int out_size, void* d_ws, size_t ws_size,
                              hipStream_t stream) {
    const float* text  = (const float*)d_in[0];
    const float* shape = (const float*)d_in[1];
    float* out = (float*)d_out;
    char* ws = (char*)d_ws;

    unsigned short* Xt = (unsigned short*)ws;
    unsigned short* Xm = (unsigned short*)(ws + 2u * 1024u * 1024u);
    float* R = (float*)(ws + 4u * 1024u * 1024u);

    convert_kernel<<<(B_ROWS * E_COLS / 4 + 255) / 256, 256, 0, stream>>>(
        text, shape, Xt, Xm, R, out);

    dim3 grid(NSTRIP, 4, 2);                     // 128 strips x 4 splits x 2 layers
    gemm_rowsum_kernel<<<grid, 256, 0, stream>>>(Xt, Xm, R);

    finalize_kernel<<<256, 256, 0, stream>>>(text, shape, R, out);
}

// Round 7
// 44.528 us; speedup vs baseline: 2.4334x; 2.4334x over previous
//
#include <hip/hip_runtime.h>
#include <hip/hip_bf16.h>

// ---------------------------------------------------------------------------
// Metric_Loss: two fused (X X^T/128 -> exp(1+.) -> row-sum) passes + pair combine.
// B=8192, E=128, P=4096.  Output: scalar f32 = metric_tt + metric_st.
//
// Round 7: fp8(e4m3) GEMM at the R4 LDS skeleton. Halves staging bytes, LDS,
// ds_reads, frag registers; 64-row strips with 8 h-splits -> 2048 blocks,
// ~6-8 blocks/CU resident (deep barrier-domain diversity per SIMD).
// Pre-scale by sqrt(log2e/128) -> acc = D*log2e, epilogue is 1 exp2/element.
// Dij/diag-block terms computed exactly in f32 by finalize (fp8 err cancels).
//
// ws layout:
//   [0, 1MB)        Xt fp8    [8192][128]   scaled by sqrt(log2e/128)
//   [1MB, 2MB)      Xm fp8    [8192][128]   (mixed: even=text, odd=shape[r>>1])
//   [2MB, 2MB+64KB) R f32     [2][8192]     row sums of exp(1+D)
// ---------------------------------------------------------------------------

#define B_ROWS 8192
#define E_COLS 128
#define P_PAIRS 4096
#define NSTRIP 128              // 64-row strips
#define NH 8                    // h-splits per strip

using f32x4 = __attribute__((ext_vector_type(4))) float;

// sqrt(log2(e)/128): MFMA yields acc = D*log2(e); exp(1+D) = e * exp2(acc)
#define BF_SCALE 0.106164482742544f
#define EULER    2.718281828459045f

// --------------------------- conversion kernel -----------------------------
__device__ __forceinline__ unsigned pk4_fp8(float a, float b, float c, float d) {
    unsigned v = 0;
    v = __builtin_amdgcn_cvt_pk_fp8_f32(a * BF_SCALE, b * BF_SCALE, v, false);
    v = __builtin_amdgcn_cvt_pk_fp8_f32(c * BF_SCALE, d * BF_SCALE, v, true);
    return v;
}

__global__ void convert_kernel(const float* __restrict__ text,
                               const float* __restrict__ shape,
                               unsigned* __restrict__ Xt,     // fp8 x4 per word
                               unsigned* __restrict__ Xm,
                               float* __restrict__ R,
                               float* __restrict__ out) {
    int idx = blockIdx.x * blockDim.x + threadIdx.x;     // 4 elements per thread
    if (idx < 4096) {                                    // zero R (2*8192 f32)
        float4 z; z.x = z.y = z.z = z.w = 0.f;
        ((float4*)R)[idx] = z;
    }
    if (idx == 0) *out = 0.f;
    int e = idx * 4;
    if (e >= B_ROWS * E_COLS) return;
    float4 t = *(const float4*)(text + e);
    unsigned tp = pk4_fp8(t.x, t.y, t.z, t.w);
    Xt[idx] = tp;
    int row = e >> 7;
    if (row & 1) {
        int col = e & 127;
        float4 s = *(const float4*)(shape + (row >> 1) * E_COLS + col);
        Xm[idx] = pk4_fp8(s.x, s.y, s.z, s.w);
    } else {
        Xm[idx] = tp;
    }
}

// --------------------------- fused GEMM + rowsum (fp8) ---------------------
// LDS tile: 64 rows x 128B (fp8). Linear dest for global_load_lds; read-side
// XOR swizzle (16B granule) applied to the pre-swizzled global source.
__device__ __forceinline__ int lds_off(int row, int k0) {
    return (row << 7) + (k0 ^ ((row & 7) << 4));
}

// Stage one 64x128 fp8 tile (8KB): 2 iters of 256 threads x 16B.
__device__ __forceinline__ void stage8k(const char* gsrc, char* ldst, int tid) {
#pragma unroll
    for (int it = 0; it < 2; ++it) {
        int L   = it * 4096 + tid * 16;
        int row = L >> 7;
        int cb  = L & 127;
        int src = (row << 7) + (cb ^ ((row & 7) << 4));
        __builtin_amdgcn_global_load_lds(
            (const __attribute__((address_space(1))) void*)(gsrc + src),
            (__attribute__((address_space(3))) void*)(ldst + L), 16, 0, 0);
    }
}

// Block = (strip bm in 0..127, split h in 0..7, layer l). Strip = 64 A-rows.
// Tiles (bm, bn=(bm+t)&127): t in {1..63} each unordered pair once; t==64
// gated bm<64 (h==0); t==0 diagonal (h==0, from buf0). Wave: 32x32 quadrant.
__launch_bounds__(256, 6)
__global__ void gemm_rowsum_kernel(const unsigned char* __restrict__ Xt,
                                   const unsigned char* __restrict__ Xm,
                                   float* __restrict__ R) {
    const int bm = blockIdx.x, h = blockIdx.y, l = blockIdx.z;
    const char* gX = (const char*)(l ? Xm : Xt);

    __shared__ __align__(16) char buf0[64 * 128];
    __shared__ __align__(16) char buf1[64 * 128];
    const int tid = threadIdx.x;

    const int t0 = (h == 0) ? NH : h;
    const int N  = (h == 0) ? (bm < 64 ? 8 : 7) : 8;     // off-diag tile count

    // ---- prologue: stage A -> buf0, first B -> buf1 ----
    stage8k(gX + bm * 8192, buf0, tid);
    stage8k(gX + ((bm + t0) & 127) * 8192, buf1, tid);
    asm volatile("s_waitcnt vmcnt(2)" ::: "memory");     // A landed
    __builtin_amdgcn_s_barrier();

    const int lane = tid & 63;
    const int w  = tid >> 6;
    const int wr = w >> 1, wc = w & 1;
    const int rA0 = wr * 32 + (lane & 15);
    const int rB0 = wc * 32 + (lane & 15);
    const int k8  = (lane >> 4) * 8;             // byte offset of lane's k-slice

    // ---- hoist A fragments (4 kk x 2 m, 8B each) ----
    long afr[4][2];
#pragma unroll
    for (int kk = 0; kk < 4; ++kk)
#pragma unroll
        for (int m = 0; m < 2; ++m)
            afr[kk][m] = *(const long*)(buf0 + lds_off(rA0 + m * 16, kk * 32 + k8));

    float s_r[2][4] = {{0.f}};                   // persistent row partials [m][j]

    // ---- diagonal tile (h==0): B-frags also from buf0; rows only ----
    if (h == 0) {
        f32x4 acc[2][2] = {};
#pragma unroll
        for (int kk = 0; kk < 4; ++kk) {
            long bfr[2];
#pragma unroll
            for (int n = 0; n < 2; ++n)
                bfr[n] = *(const long*)(buf0 + lds_off(rB0 + n * 16, kk * 32 + k8));
#pragma unroll
            for (int m = 0; m < 2; ++m)
#pragma unroll
                for (int n = 0; n < 2; ++n)
                    acc[m][n] = __builtin_amdgcn_mfma_f32_16x16x32_fp8_fp8(
                        afr[kk][m], bfr[n], acc[m][n], 0, 0, 0);
        }
#pragma unroll
        for (int m = 0; m < 2; ++m)
#pragma unroll
            for (int n = 0; n < 2; ++n)
#pragma unroll
                for (int j = 0; j < 4; ++j)
                    s_r[m][j] += __builtin_amdgcn_exp2f(acc[m][n][j]);
    }

    // ---- all buf0 reads done before it becomes a B buffer ----
    asm volatile("s_waitcnt lgkmcnt(0)" ::: "memory");
    __builtin_amdgcn_s_barrier();

    // ---- 2-phase pipelined loop over off-diagonal tiles ----
    int cur = 1;                                 // current B buffer: 1 -> buf1
    for (int idx = 0; idx < N; ++idx) {
        const bool hasnext = (idx + 1 < N);
        if (hasnext)
            stage8k(gX + ((bm + t0 + NH * (idx + 1)) & 127) * 8192,
                    cur ? buf0 : buf1, tid);

        if (hasnext) { asm volatile("s_waitcnt vmcnt(2)" ::: "memory"); }
        else         { asm volatile("s_waitcnt vmcnt(0)" ::: "memory"); }
        __builtin_amdgcn_s_barrier();            // cur buffer staged (all waves)

        const char* lsrc = cur ? buf1 : buf0;
        f32x4 acc[2][2] = {};
#pragma unroll
        for (int kk = 0; kk < 4; ++kk) {
            long bfr[2];
#pragma unroll
            for (int n = 0; n < 2; ++n)
                bfr[n] = *(const long*)(lsrc + lds_off(rB0 + n * 16, kk * 32 + k8));
#pragma unroll
            for (int m = 0; m < 2; ++m)
#pragma unroll
                for (int n = 0; n < 2; ++n)
                    acc[m][n] = __builtin_amdgcn_mfma_f32_16x16x32_fp8_fp8(
                        afr[kk][m], bfr[n], acc[m][n], 0, 0, 0);
        }

        asm volatile("s_waitcnt lgkmcnt(0)" ::: "memory");
        __builtin_amdgcn_s_barrier();            // cur reads done -> overwritable

        // ---- epilogue: rows -> regs, cols -> shuffle + atomics ----
        const int bn = (bm + t0 + NH * idx) & 127;
        float s_c[2] = {0.f, 0.f};
#pragma unroll
        for (int m = 0; m < 2; ++m)
#pragma unroll
            for (int n = 0; n < 2; ++n)
#pragma unroll
                for (int j = 0; j < 4; ++j) {
                    float e2 = __builtin_amdgcn_exp2f(acc[m][n][j]);
                    s_r[m][j] += e2;
                    s_c[n] += e2;
                }
#pragma unroll
        for (int n = 0; n < 2; ++n) {
            float v = s_c[n];
            v += __shfl_xor(v, 16, 64);
            v += __shfl_xor(v, 32, 64);
            if (lane < 16) {
                int gcol = bn * 64 + wc * 32 + n * 16 + lane;
                atomicAdd(&R[l * B_ROWS + gcol], EULER * v);
            }
        }
        cur ^= 1;
    }

    // ---- final row reduction (once per block) ----
#pragma unroll
    for (int m = 0; m < 2; ++m)
#pragma unroll
        for (int j = 0; j < 4; ++j) {
            float v = s_r[m][j];
            v += __shfl_xor(v, 1, 64);
            v += __shfl_xor(v, 2, 64);
            v += __shfl_xor(v, 4, 64);
            v += __shfl_xor(v, 8, 64);
            if ((lane & 15) == 0) {
                int grow = bm * 64 + wr * 32 + m * 16 + (lane >> 4) * 4 + j;
                atomicAdd(&R[l * B_ROWS + grow], EULER * v);
            }
        }
}

// --------------------------- finalize --------------------------------------
__global__ void finalize_kernel(const float* __restrict__ text,
                                const float* __restrict__ shape,
                                const float* __restrict__ R,
                                float* __restrict__ out) {
    const int tid = threadIdx.x;
    const int lane = tid & 63;
    const int w = tid >> 6;
    const int waveGlobal = blockIdx.x * 4 + w;   // 1024 waves total
    const float inv128 = 0.0078125f;
    float accum = 0.f;

    for (int task = waveGlobal; task < 2 * P_PAIRS; task += 1024) {
        int l = task >> 12;
        int p = task & (P_PAIRS - 1);
        const float* a = text + (2 * p) * E_COLS;                       // even row: always text
        const float* b = l ? (shape + p * E_COLS) : (text + (2 * p + 1) * E_COLS);
        float2 av = *(const float2*)(a + lane * 2);
        float2 bv = *(const float2*)(b + lane * 2);
        float dii = av.x * av.x + av.y * av.y;
        float djj = bv.x * bv.x + bv.y * bv.y;
        float dij = av.x * bv.x + av.y * bv.y;
#pragma unroll
        for (int sh = 1; sh < 64; sh <<= 1) {
            dii += __shfl_xor(dii, sh, 64);
            djj += __shfl_xor(djj, sh, 64);
            dij += __shfl_xor(dij, sh, 64);
        }
        if (lane == 0) {
            float Dii = dii * inv128, Djj = djj * inv128, Dij = dij * inv128;
            float S = R[l * B_ROWS + 2 * p] + R[l * B_ROWS + 2 * p + 1]
                    - (__expf(1.f + Dii) + 2.f * __expf(1.f + Dij) + __expf(1.f + Djj));
            float J = __logf(S) - Dij;
            accum += 0.5f * J * J * (1.0f / (float)P_PAIRS);
        }
    }

    __shared__ float red[4];
    if (lane == 0) red[w] = accum;
    __syncthreads();
    if (tid == 0) {
        atomicAdd(out, red[0] + red[1] + red[2] + red[3]);
    }
}

// --------------------------- launch ----------------------------------------
extern "C" void kernel_launch(void* const* d_in, const int* in_sizes, int n_in,
                              void* d_out, int out_size, void* d_ws, size_t ws_size,
                              hipStream_t stream) {
    const float* text  = (const float*)d_in[0];
    const float* shape = (const float*)d_in[1];
    float* out = (float*)d_out;
    char* ws = (char*)d_ws;

    unsigned char* Xt = (unsigned char*)ws;
    unsigned char* Xm = (unsigned char*)(ws + 1u * 1024u * 1024u);
    float* R = (float*)(ws + 2u * 1024u * 1024u);

    convert_kernel<<<(B_ROWS * E_COLS / 4 + 255) / 256, 256, 0, stream>>>(
        text, shape, (unsigned*)Xt, (unsigned*)Xm, R, out);

    dim3 grid(NSTRIP, NH, 2);                    // 128 strips x 8 splits x 2 layers
    gemm_rowsum_kernel<<<grid, 256, 0, stream>>>(Xt, Xm, R);

    finalize_kernel<<<256, 256, 0, stream>>>(text, shape, R, out);
}

// Round 8
// 42.430 us; speedup vs baseline: 2.5538x; 1.0495x over previous
//
#include <hip/hip_runtime.h>
#include <hip/hip_bf16.h>

// ---------------------------------------------------------------------------
// Metric_Loss: two fused (X X^T/128 -> exp(1+.) -> row-sum) passes + pair combine.
// B=8192, E=128, P=4096.  Output: scalar f32 = metric_tt + metric_st.
//
// Round 8: MX-scaled fp8 GEMM (mfma_scale_f32_16x16x128_f8f6f4, unit scales).
// One MFMA instruction per 16x16 output covers the FULL K=128: 4x fewer MFMA
// issues at 2x rate vs R7's non-scaled fp8. Same R7 skeleton otherwise
// (64-row strips, 8 h-splits, 2-phase counted-vmcnt LDS pipeline, symmetry,
// exp2 pre-scale sqrt(log2e/128), exact-f32 finalize).
//
// ws layout:
//   [0, 1MB)        Xt fp8    [8192][128]   scaled by sqrt(log2e/128)
//   [1MB, 2MB)      Xm fp8    [8192][128]   (mixed: even=text, odd=shape[r>>1])
//   [2MB, 2MB+64KB) R f32     [2][8192]     row sums of exp(1+D)
// ---------------------------------------------------------------------------

#define B_ROWS 8192
#define E_COLS 128
#define P_PAIRS 4096
#define NSTRIP 128              // 64-row strips
#define NH 8                    // h-splits per strip

using f32x4 = __attribute__((ext_vector_type(4))) float;
using i32x8 = __attribute__((ext_vector_type(8))) int;

// sqrt(log2(e)/128): MFMA yields acc = D*log2(e); exp(1+D) = e * exp2(acc)
#define BF_SCALE 0.106164482742544f
#define EULER    2.718281828459045f
#define SCALE1   0x7f            // E8M0 exponent 127 -> 2^0 (unit scale)

// --------------------------- conversion kernel -----------------------------
__device__ __forceinline__ unsigned pk4_fp8(float a, float b, float c, float d) {
    unsigned v = 0;
    v = __builtin_amdgcn_cvt_pk_fp8_f32(a * BF_SCALE, b * BF_SCALE, v, false);
    v = __builtin_amdgcn_cvt_pk_fp8_f32(c * BF_SCALE, d * BF_SCALE, v, true);
    return v;
}

__global__ void convert_kernel(const float* __restrict__ text,
                               const float* __restrict__ shape,
                               unsigned* __restrict__ Xt,     // fp8 x4 per word
                               unsigned* __restrict__ Xm,
                               float* __restrict__ R,
                               float* __restrict__ out) {
    int idx = blockIdx.x * blockDim.x + threadIdx.x;     // 4 elements per thread
    if (idx < 4096) {                                    // zero R (2*8192 f32)
        float4 z; z.x = z.y = z.z = z.w = 0.f;
        ((float4*)R)[idx] = z;
    }
    if (idx == 0) *out = 0.f;
    int e = idx * 4;
    if (e >= B_ROWS * E_COLS) return;
    float4 t = *(const float4*)(text + e);
    unsigned tp = pk4_fp8(t.x, t.y, t.z, t.w);
    Xt[idx] = tp;
    int row = e >> 7;
    if (row & 1) {
        int col = e & 127;
        float4 s = *(const float4*)(shape + (row >> 1) * E_COLS + col);
        Xm[idx] = pk4_fp8(s.x, s.y, s.z, s.w);
    } else {
        Xm[idx] = tp;
    }
}

// --------------------------- fused GEMM + rowsum (MX-fp8) ------------------
// LDS tile: 64 rows x 128B (fp8). Linear dest for global_load_lds; read-side
// XOR swizzle (16B granule) applied to the pre-swizzled global source.
__device__ __forceinline__ int lds_off(int row, int k0) {
    return (row << 7) + (k0 ^ ((row & 7) << 4));
}

// Load a K=128 fragment: 32 contiguous fp8 at (row, k32) as two swizzled b128.
__device__ __forceinline__ i32x8 load_frag32(const char* base, int row, int k32) {
    union { i32x8 v; int4 h[2]; } u;
    u.h[0] = *(const int4*)(base + lds_off(row, k32));
    u.h[1] = *(const int4*)(base + lds_off(row, k32 + 16));
    return u.v;
}

// Stage one 64x128 fp8 tile (8KB): 2 iters of 256 threads x 16B.
__device__ __forceinline__ void stage8k(const char* gsrc, char* ldst, int tid) {
#pragma unroll
    for (int it = 0; it < 2; ++it) {
        int L   = it * 4096 + tid * 16;
        int row = L >> 7;
        int cb  = L & 127;
        int src = (row << 7) + (cb ^ ((row & 7) << 4));
        __builtin_amdgcn_global_load_lds(
            (const __attribute__((address_space(1))) void*)(gsrc + src),
            (__attribute__((address_space(3))) void*)(ldst + L), 16, 0, 0);
    }
}

// Block = (strip bm in 0..127, split h in 0..7, layer l). Strip = 64 A-rows.
// Tiles (bm, bn=(bm+t)&127): t in {1..63} each unordered pair once; t==64
// gated bm<64 (h==0); t==0 diagonal (h==0, from buf0). Wave: 32x32 quadrant.
__launch_bounds__(256, 6)
__global__ void gemm_rowsum_kernel(const unsigned char* __restrict__ Xt,
                                   const unsigned char* __restrict__ Xm,
                                   float* __restrict__ R) {
    const int bm = blockIdx.x, h = blockIdx.y, l = blockIdx.z;
    const char* gX = (const char*)(l ? Xm : Xt);

    __shared__ __align__(16) char buf0[64 * 128];
    __shared__ __align__(16) char buf1[64 * 128];
    const int tid = threadIdx.x;

    const int t0 = (h == 0) ? NH : h;
    const int N  = (h == 0) ? (bm < 64 ? 8 : 7) : 8;     // off-diag tile count

    // ---- prologue: stage A -> buf0, first B -> buf1 ----
    stage8k(gX + bm * 8192, buf0, tid);
    stage8k(gX + ((bm + t0) & 127) * 8192, buf1, tid);
    asm volatile("s_waitcnt vmcnt(2)" ::: "memory");     // A landed
    __builtin_amdgcn_s_barrier();

    const int lane = tid & 63;
    const int w  = tid >> 6;
    const int wr = w >> 1, wc = w & 1;
    const int rA0 = wr * 32 + (lane & 15);
    const int rB0 = wc * 32 + (lane & 15);
    const int k32 = (lane >> 4) * 32;            // byte offset of lane's K-slice

    // ---- hoist A fragments (2 m-frags, full K=128 each) ----
    i32x8 afr[2];
#pragma unroll
    for (int m = 0; m < 2; ++m)
        afr[m] = load_frag32(buf0, rA0 + m * 16, k32);

    float s_r[2][4] = {{0.f}};                   // persistent row partials [m][j]

    // ---- diagonal tile (h==0): B-frags also from buf0; rows only ----
    if (h == 0) {
        i32x8 bfr[2];
#pragma unroll
        for (int n = 0; n < 2; ++n)
            bfr[n] = load_frag32(buf0, rB0 + n * 16, k32);
        f32x4 acc[2][2] = {};
#pragma unroll
        for (int m = 0; m < 2; ++m)
#pragma unroll
            for (int n = 0; n < 2; ++n)
                acc[m][n] = __builtin_amdgcn_mfma_scale_f32_16x16x128_f8f6f4(
                    afr[m], bfr[n], acc[m][n], 0, 0, 0, SCALE1, 0, SCALE1);
#pragma unroll
        for (int m = 0; m < 2; ++m)
#pragma unroll
            for (int n = 0; n < 2; ++n)
#pragma unroll
                for (int j = 0; j < 4; ++j)
                    s_r[m][j] += __builtin_amdgcn_exp2f(acc[m][n][j]);
    }

    // ---- all buf0 reads done before it becomes a B buffer ----
    asm volatile("s_waitcnt lgkmcnt(0)" ::: "memory");
    __builtin_amdgcn_s_barrier();

    // ---- 2-phase pipelined loop over off-diagonal tiles ----
    int cur = 1;                                 // current B buffer: 1 -> buf1
    for (int idx = 0; idx < N; ++idx) {
        const bool hasnext = (idx + 1 < N);
        if (hasnext)
            stage8k(gX + ((bm + t0 + NH * (idx + 1)) & 127) * 8192,
                    cur ? buf0 : buf1, tid);

        if (hasnext) { asm volatile("s_waitcnt vmcnt(2)" ::: "memory"); }
        else         { asm volatile("s_waitcnt vmcnt(0)" ::: "memory"); }
        __builtin_amdgcn_s_barrier();            // cur buffer staged (all waves)

        const char* lsrc = cur ? buf1 : buf0;
        i32x8 bfr[2];
#pragma unroll
        for (int n = 0; n < 2; ++n)
            bfr[n] = load_frag32(lsrc, rB0 + n * 16, k32);
        f32x4 acc[2][2] = {};
#pragma unroll
        for (int m = 0; m < 2; ++m)
#pragma unroll
            for (int n = 0; n < 2; ++n)
                acc[m][n] = __builtin_amdgcn_mfma_scale_f32_16x16x128_f8f6f4(
                    afr[m], bfr[n], acc[m][n], 0, 0, 0, SCALE1, 0, SCALE1);

        asm volatile("s_waitcnt lgkmcnt(0)" ::: "memory");
        __builtin_amdgcn_s_barrier();            // cur reads done -> overwritable

        // ---- epilogue: rows -> regs, cols -> shuffle + atomics ----
        const int bn = (bm + t0 + NH * idx) & 127;
        float s_c[2] = {0.f, 0.f};
#pragma unroll
        for (int m = 0; m < 2; ++m)
#pragma unroll
            for (int n = 0; n < 2; ++n)
#pragma unroll
                for (int j = 0; j < 4; ++j) {
                    float e2 = __builtin_amdgcn_exp2f(acc[m][n][j]);
                    s_r[m][j] += e2;
                    s_c[n] += e2;
                }
#pragma unroll
        for (int n = 0; n < 2; ++n) {
            float v = s_c[n];
            v += __shfl_xor(v, 16, 64);
            v += __shfl_xor(v, 32, 64);
            if (lane < 16) {
                int gcol = bn * 64 + wc * 32 + n * 16 + lane;
                atomicAdd(&R[l * B_ROWS + gcol], EULER * v);
            }
        }
        cur ^= 1;
    }

    // ---- final row reduction (once per block) ----
#pragma unroll
    for (int m = 0; m < 2; ++m)
#pragma unroll
        for (int j = 0; j < 4; ++j) {
            float v = s_r[m][j];
            v += __shfl_xor(v, 1, 64);
            v += __shfl_xor(v, 2, 64);
            v += __shfl_xor(v, 4, 64);
            v += __shfl_xor(v, 8, 64);
            if ((lane & 15) == 0) {
                int grow = bm * 64 + wr * 32 + m * 16 + (lane >> 4) * 4 + j;
                atomicAdd(&R[l * B_ROWS + grow], EULER * v);
            }
        }
}

// --------------------------- finalize --------------------------------------
__global__ void finalize_kernel(const float* __restrict__ text,
                                const float* __restrict__ shape,
                                const float* __restrict__ R,
                                float* __restrict__ out) {
    const int tid = threadIdx.x;
    const int lane = tid & 63;
    const int w = tid >> 6;
    const int waveGlobal = blockIdx.x * 4 + w;   // 1024 waves total
    const float inv128 = 0.0078125f;
    float accum = 0.f;

    for (int task = waveGlobal; task < 2 * P_PAIRS; task += 1024) {
        int l = task >> 12;
        int p = task & (P_PAIRS - 1);
        const float* a = text + (2 * p) * E_COLS;                       // even row: always text
        const float* b = l ? (shape + p * E_COLS) : (text + (2 * p + 1) * E_COLS);
        float2 av = *(const float2*)(a + lane * 2);
        float2 bv = *(const float2*)(b + lane * 2);
        float dii = av.x * av.x + av.y * av.y;
        float djj = bv.x * bv.x + bv.y * bv.y;
        float dij = av.x * bv.x + av.y * bv.y;
#pragma unroll
        for (int sh = 1; sh < 64; sh <<= 1) {
            dii += __shfl_xor(dii, sh, 64);
            djj += __shfl_xor(djj, sh, 64);
            dij += __shfl_xor(dij, sh, 64);
        }
        if (lane == 0) {
            float Dii = dii * inv128, Djj = djj * inv128, Dij = dij * inv128;
            float S = R[l * B_ROWS + 2 * p] + R[l * B_ROWS + 2 * p + 1]
                    - (__expf(1.f + Dii) + 2.f * __expf(1.f + Dij) + __expf(1.f + Djj));
            float J = __logf(S) - Dij;
            accum += 0.5f * J * J * (1.0f / (float)P_PAIRS);
        }
    }

    __shared__ float red[4];
    if (lane == 0) red[w] = accum;
    __syncthreads();
    if (tid == 0) {
        atomicAdd(out, red[0] + red[1] + red[2] + red[3]);
    }
}

// --------------------------- launch ----------------------------------------
extern "C" void kernel_launch(void* const* d_in, const int* in_sizes, int n_in,
                              void* d_out, int out_size, void* d_ws, size_t ws_size,
                              hipStream_t stream) {
    const float* text  = (const float*)d_in[0];
    const float* shape = (const float*)d_in[1];
    float* out = (float*)d_out;
    char* ws = (char*)d_ws;

    unsigned char* Xt = (unsigned char*)ws;
    unsigned char* Xm = (unsigned char*)(ws + 1u * 1024u * 1024u);
    float* R = (float*)(ws + 2u * 1024u * 1024u);

    convert_kernel<<<(B_ROWS * E_COLS / 4 + 255) / 256, 256, 0, stream>>>(
        text, shape, (unsigned*)Xt, (unsigned*)Xm, R, out);

    dim3 grid(NSTRIP, NH, 2);                    // 128 strips x 8 splits x 2 layers
    gemm_rowsum_kernel<<<grid, 256, 0, stream>>>(Xt, Xm, R);

    finalize_kernel<<<256, 256, 0, stream>>>(text, shape, R, out);
}